// Round 1
// baseline (393.993 us; speedup 1.0000x reference)
//
#include <hip/hip_runtime.h>

#define N_NODES 50000
#define E_EDGES 800000

// ---------------------------------------------------------------------------
// Projection kernel: xq = q@Wq+bq, xk = k@Wk+bk, xv = v@Wv+bv  (N x 64 each)
// Block: 256 threads -> 64 rows x 64 cols per block. Thread = 4 rows x 4 cols
// per matrix. Weights staged in LDS (48 KB); rows read as float4 from global.
// ---------------------------------------------------------------------------
__global__ __launch_bounds__(256) void proj_kernel(
    const float* __restrict__ qin, const float* __restrict__ kin, const float* __restrict__ vin,
    const float* __restrict__ Wq, const float* __restrict__ bq,
    const float* __restrict__ Wk, const float* __restrict__ bk,
    const float* __restrict__ Wv, const float* __restrict__ bv,
    float* __restrict__ xq, float* __restrict__ xk, float* __restrict__ xv)
{
    __shared__ float Ws[3 * 4096];
    const int tid = threadIdx.x;
    #pragma unroll
    for (int it = 0; it < 16; ++it) {
        const int idx = it * 256 + tid;
        Ws[idx]        = Wq[idx];
        Ws[4096 + idx] = Wk[idx];
        Ws[8192 + idx] = Wv[idx];
    }
    __syncthreads();

    const int cg = tid & 15;   // column group (4 cols)
    const int rg = tid >> 4;   // row group (4 rows)
    const int c0 = cg * 4;
    const int base = blockIdx.x * 64 + rg * 4;

    const float* ins[3]  = {qin, kin, vin};
    const float* bs[3]   = {bq, bk, bv};
    float*       outs[3] = {xq, xk, xv};

    int rowi[4];
    #pragma unroll
    for (int rr = 0; rr < 4; ++rr)
        rowi[rr] = (base + rr < N_NODES) ? (base + rr) : (N_NODES - 1);

    #pragma unroll
    for (int m = 0; m < 3; ++m) {
        const float* in = ins[m];
        const float* Wm = &Ws[m * 4096];
        float4 acc[4];
        const float4 b4 = *reinterpret_cast<const float4*>(&bs[m][c0]);
        #pragma unroll
        for (int rr = 0; rr < 4; ++rr) acc[rr] = b4;

        for (int kk = 0; kk < 64; kk += 4) {
            float4 rv[4];
            #pragma unroll
            for (int rr = 0; rr < 4; ++rr)
                rv[rr] = *reinterpret_cast<const float4*>(&in[rowi[rr] * 64 + kk]);
            #pragma unroll
            for (int dk = 0; dk < 4; ++dk) {
                const float4 w4 = *reinterpret_cast<const float4*>(&Wm[(kk + dk) * 64 + c0]);
                #pragma unroll
                for (int rr = 0; rr < 4; ++rr) {
                    const float xs = reinterpret_cast<const float*>(&rv[rr])[dk];
                    acc[rr].x = fmaf(xs, w4.x, acc[rr].x);
                    acc[rr].y = fmaf(xs, w4.y, acc[rr].y);
                    acc[rr].z = fmaf(xs, w4.z, acc[rr].z);
                    acc[rr].w = fmaf(xs, w4.w, acc[rr].w);
                }
            }
        }
        #pragma unroll
        for (int rr = 0; rr < 4; ++rr) {
            if (base + rr < N_NODES)
                *reinterpret_cast<float4*>(&outs[m][(base + rr) * 64 + c0]) = acc[rr];
        }
    }
}

// ---------------------------------------------------------------------------
// Edge kernel: octet (8 lanes) per edge. Lane r owns channels c = 8*i + r
// (so c & 7 == r -> softmax weight is lane-local).
// Per wave: 8 octets = 8 edges per iteration, 8 iterations -> 64 edges/wave.
// Block 256 threads = 4 waves = 256 edges. Grid = E/256 = 3125 (exact).
// ---------------------------------------------------------------------------
__global__ __launch_bounds__(256) void edge_kernel(
    const float* __restrict__ edges, const int* __restrict__ eidx,
    const float* __restrict__ Wp, const float* __restrict__ bp,
    const float* __restrict__ W1, const float* __restrict__ b1,
    const float* __restrict__ W2, const float* __restrict__ b2,
    const float* __restrict__ xq, const float* __restrict__ xk, const float* __restrict__ xv,
    float* __restrict__ out)
{
    const int tid  = threadIdx.x;
    const int lane = tid & 63;
    const int o    = lane >> 3;   // octet within wave (edge slot)
    const int r    = lane & 7;    // lane within octet
    const int wave = tid >> 6;

    // ---- preload weights into registers (amortized over 64 edges) ----
    float W1reg[8][8];   // W1 rows c = 8*i + r, all 8 output cols
    #pragma unroll
    for (int i = 0; i < 8; ++i) {
        const float4 a = *reinterpret_cast<const float4*>(&W1[(8 * i + r) * 8]);
        const float4 b = *reinterpret_cast<const float4*>(&W1[(8 * i + r) * 8 + 4]);
        W1reg[i][0] = a.x; W1reg[i][1] = a.y; W1reg[i][2] = a.z; W1reg[i][3] = a.w;
        W1reg[i][4] = b.x; W1reg[i][5] = b.y; W1reg[i][6] = b.z; W1reg[i][7] = b.w;
    }
    float W2col[8];
    #pragma unroll
    for (int i = 0; i < 8; ++i) W2col[i] = W2[i * 8 + r];
    float b1reg[8];
    #pragma unroll
    for (int j = 0; j < 8; ++j) b1reg[j] = b1[j];
    const float b2r = b2[r];
    const float wp0 = Wp[r], wp1 = Wp[8 + r];
    const float bp0 = bp[0];

    const int base = (blockIdx.x * 4 + wave) * 64;

    for (int t = 0; t < 8; ++t) {
        const int e   = base + t * 8 + o;
        const int src = eidx[2 * e];
        const int dst = eidx[2 * e + 1];

        // ---- p_r = edges[e] . Wp + bp (16-dot across octet) ----
        float ep = edges[e * 16 + r] * wp0 + edges[e * 16 + 8 + r] * wp1;
        ep += __shfl_xor(ep, 1);
        ep += __shfl_xor(ep, 2);
        ep += __shfl_xor(ep, 4);
        const float p = ep + bp0;

        // ---- h1 partials: relu(xk - xq + p) @ W1 ----
        float part[8];
        #pragma unroll
        for (int j = 0; j < 8; ++j) part[j] = 0.f;
        #pragma unroll
        for (int i = 0; i < 8; ++i) {
            const int c = 8 * i + r;
            const float a = xk[dst * 64 + c] - xq[src * 64 + c] + p;
            const float ar = fmaxf(a, 0.f);
            #pragma unroll
            for (int j = 0; j < 8; ++j)
                part[j] = fmaf(ar, W1reg[i][j], part[j]);
        }
        #pragma unroll
        for (int j = 0; j < 8; ++j) {
            part[j] += __shfl_xor(part[j], 1);
            part[j] += __shfl_xor(part[j], 2);
            part[j] += __shfl_xor(part[j], 4);
        }

        // ---- h2[r] = b2[r] + relu(h1) . W2[:, r] ----
        float h2 = b2r;
        #pragma unroll
        for (int j = 0; j < 8; ++j) {
            const float h1 = fmaxf(part[j] + b1reg[j], 0.f);
            h2 = fmaf(h1, W2col[j], h2);
        }

        // ---- softmax over the 8 lanes of the octet ----
        float mx = h2;
        mx = fmaxf(mx, __shfl_xor(mx, 1));
        mx = fmaxf(mx, __shfl_xor(mx, 2));
        mx = fmaxf(mx, __shfl_xor(mx, 4));
        const float ex = __expf(h2 - mx);
        float s = ex;
        s += __shfl_xor(s, 1);
        s += __shfl_xor(s, 2);
        s += __shfl_xor(s, 4);
        const float sel = ex / s;

        // ---- msg = (xv + p) * sel, scatter-add into out[src] ----
        #pragma unroll
        for (int i = 0; i < 8; ++i) {
            const int c = 8 * i + r;
            const float msg = (xv[dst * 64 + c] + p) * sel;
            atomicAdd(&out[src * 64 + c], msg);
        }
    }
}

extern "C" void kernel_launch(void* const* d_in, const int* in_sizes, int n_in,
                              void* d_out, int out_size, void* d_ws, size_t ws_size,
                              hipStream_t stream) {
    const float* q     = (const float*)d_in[0];
    const float* k     = (const float*)d_in[1];
    const float* v     = (const float*)d_in[2];
    const float* edges = (const float*)d_in[3];
    const int*   eidx  = (const int*)d_in[4];
    const float* Wq    = (const float*)d_in[5];
    const float* bq    = (const float*)d_in[6];
    const float* Wk    = (const float*)d_in[7];
    const float* bk    = (const float*)d_in[8];
    const float* Wv    = (const float*)d_in[9];
    const float* bv    = (const float*)d_in[10];
    const float* Wp    = (const float*)d_in[11];
    const float* bp    = (const float*)d_in[12];
    const float* W1    = (const float*)d_in[13];
    const float* b1    = (const float*)d_in[14];
    const float* W2    = (const float*)d_in[15];
    const float* b2    = (const float*)d_in[16];
    float* out = (float*)d_out;

    float* xq = (float*)d_ws;
    float* xk = xq + (size_t)N_NODES * 64;
    float* xv = xk + (size_t)N_NODES * 64;

    // output is accumulated atomically -> must be zeroed every launch
    hipMemsetAsync(d_out, 0, (size_t)N_NODES * 64 * sizeof(float), stream);

    proj_kernel<<<dim3((N_NODES + 63) / 64), dim3(256), 0, stream>>>(
        q, k, v, Wq, bq, Wk, bk, Wv, bv, xq, xk, xv);

    edge_kernel<<<dim3(E_EDGES / 256), dim3(256), 0, stream>>>(
        edges, eidx, Wp, bp, W1, b1, W2, b2, xq, xk, xv, out);
}

// Round 2
// 332.267 us; speedup vs baseline: 1.1858x; 1.1858x over previous
//
#include <hip/hip_runtime.h>

#define N_NODES 50000
#define E_EDGES 800000

// ---------------------------------------------------------------------------
// Projection kernel: xq = q@Wq+bq, xk = k@Wk+bk, xv = v@Wv+bv  (N x 64 each)
// ---------------------------------------------------------------------------
__global__ __launch_bounds__(256) void proj_kernel(
    const float* __restrict__ qin, const float* __restrict__ kin, const float* __restrict__ vin,
    const float* __restrict__ Wq, const float* __restrict__ bq,
    const float* __restrict__ Wk, const float* __restrict__ bk,
    const float* __restrict__ Wv, const float* __restrict__ bv,
    float* __restrict__ xq, float* __restrict__ xk, float* __restrict__ xv)
{
    __shared__ float Ws[3 * 4096];
    const int tid = threadIdx.x;
    #pragma unroll
    for (int it = 0; it < 16; ++it) {
        const int idx = it * 256 + tid;
        Ws[idx]        = Wq[idx];
        Ws[4096 + idx] = Wk[idx];
        Ws[8192 + idx] = Wv[idx];
    }
    __syncthreads();

    const int cg = tid & 15;   // column group (4 cols)
    const int rg = tid >> 4;   // row group (4 rows)
    const int c0 = cg * 4;
    const int base = blockIdx.x * 64 + rg * 4;

    const float* ins[3]  = {qin, kin, vin};
    const float* bs[3]   = {bq, bk, bv};
    float*       outs[3] = {xq, xk, xv};

    int rowi[4];
    #pragma unroll
    for (int rr = 0; rr < 4; ++rr)
        rowi[rr] = (base + rr < N_NODES) ? (base + rr) : (N_NODES - 1);

    #pragma unroll
    for (int m = 0; m < 3; ++m) {
        const float* in = ins[m];
        const float* Wm = &Ws[m * 4096];
        float4 acc[4];
        const float4 b4 = *reinterpret_cast<const float4*>(&bs[m][c0]);
        #pragma unroll
        for (int rr = 0; rr < 4; ++rr) acc[rr] = b4;

        for (int kk = 0; kk < 64; kk += 4) {
            float4 rv[4];
            #pragma unroll
            for (int rr = 0; rr < 4; ++rr)
                rv[rr] = *reinterpret_cast<const float4*>(&in[rowi[rr] * 64 + kk]);
            #pragma unroll
            for (int dk = 0; dk < 4; ++dk) {
                const float4 w4 = *reinterpret_cast<const float4*>(&Wm[(kk + dk) * 64 + c0]);
                #pragma unroll
                for (int rr = 0; rr < 4; ++rr) {
                    const float xs = reinterpret_cast<const float*>(&rv[rr])[dk];
                    acc[rr].x = fmaf(xs, w4.x, acc[rr].x);
                    acc[rr].y = fmaf(xs, w4.y, acc[rr].y);
                    acc[rr].z = fmaf(xs, w4.z, acc[rr].z);
                    acc[rr].w = fmaf(xs, w4.w, acc[rr].w);
                }
            }
        }
        #pragma unroll
        for (int rr = 0; rr < 4; ++rr) {
            if (base + rr < N_NODES)
                *reinterpret_cast<float4*>(&outs[m][(base + rr) * 64 + c0]) = acc[rr];
        }
    }
}

// ---------------------------------------------------------------------------
// CSR build step 1: per-src degree histogram
// ---------------------------------------------------------------------------
__global__ __launch_bounds__(256) void hist_kernel(
    const int* __restrict__ eidx, int* __restrict__ cnt)
{
    const int e = blockIdx.x * 256 + threadIdx.x;
    atomicAdd(&cnt[eidx[2 * e]], 1);
}

// ---------------------------------------------------------------------------
// CSR build step 2: exclusive scan of degrees (single block, 1024 threads).
// Writes off[0..N] and re-purposes cnt[] as the scatter cursor.
// ---------------------------------------------------------------------------
__global__ __launch_bounds__(1024) void scan_kernel(
    int* __restrict__ cnt, int* __restrict__ off)
{
    __shared__ int part[1024];
    const int tid = threadIdx.x;
    const int CHUNK = (N_NODES + 1023) / 1024;  // 49
    const int begin = tid * CHUNK;

    int s = 0;
    for (int i = 0; i < CHUNK; ++i) {
        const int idx = begin + i;
        if (idx < N_NODES) s += cnt[idx];
    }
    part[tid] = s;
    __syncthreads();
    for (int d = 1; d < 1024; d <<= 1) {
        const int t = (tid >= d) ? part[tid - d] : 0;
        __syncthreads();
        part[tid] += t;
        __syncthreads();
    }
    int run = part[tid] - s;  // exclusive prefix of this thread's chunk
    for (int i = 0; i < CHUNK; ++i) {
        const int idx = begin + i;
        if (idx < N_NODES) {
            const int c = cnt[idx];
            off[idx] = run;
            cnt[idx] = run;   // cursor for scatter
            run += c;
        }
    }
    if (tid == 0) off[N_NODES] = E_EDGES;
}

// ---------------------------------------------------------------------------
// CSR build step 3 (+ p_r precompute): for each edge, compute
// p_r = edges[e].Wp + bp (coalesced 64B row read), then scatter the
// {p_r, dst} record to its CSR slot.
// ---------------------------------------------------------------------------
__global__ __launch_bounds__(256) void scatter_kernel(
    const int* __restrict__ eidx, const float* __restrict__ edges,
    const float* __restrict__ Wp, const float* __restrict__ bp,
    int* __restrict__ cursor, float2* __restrict__ epack)
{
    const int e = blockIdx.x * 256 + threadIdx.x;
    const int src = eidx[2 * e];
    const int dst = eidx[2 * e + 1];

    float pr = bp[0];
    #pragma unroll
    for (int q4 = 0; q4 < 4; ++q4) {
        const float4 ev = *reinterpret_cast<const float4*>(&edges[e * 16 + q4 * 4]);
        const float4 wv = *reinterpret_cast<const float4*>(&Wp[q4 * 4]);
        pr = fmaf(ev.x, wv.x, pr);
        pr = fmaf(ev.y, wv.y, pr);
        pr = fmaf(ev.z, wv.z, pr);
        pr = fmaf(ev.w, wv.w, pr);
    }

    const int pos = atomicAdd(&cursor[src], 1);
    epack[pos] = make_float2(pr, __int_as_float(dst));
}

// ---------------------------------------------------------------------------
// Node kernel: one octet (8 lanes) per destination-of-aggregation node (src).
// Lane r owns channels c = 8*i + r (softmax weight index = c & 7 = r).
// Iterates the node's CSR range, accumulates the 64-ch message in registers,
// writes out[node] once. Zero float atomics.
// ---------------------------------------------------------------------------
__global__ __launch_bounds__(256) void node_kernel(
    const int* __restrict__ off, const float2* __restrict__ epack,
    const float* __restrict__ W1, const float* __restrict__ b1,
    const float* __restrict__ W2, const float* __restrict__ b2,
    const float* __restrict__ xq, const float* __restrict__ xk, const float* __restrict__ xv,
    float* __restrict__ out)
{
    const int tid  = threadIdx.x;
    const int lane = tid & 63;
    const int o    = lane >> 3;   // octet within wave
    const int r    = lane & 7;    // lane within octet
    const int wave = tid >> 6;

    // ---- preload weights into registers ----
    float W1reg[8][8];   // rows c = 8*i + r, all 8 output cols
    #pragma unroll
    for (int i = 0; i < 8; ++i) {
        const float4 a = *reinterpret_cast<const float4*>(&W1[(8 * i + r) * 8]);
        const float4 b = *reinterpret_cast<const float4*>(&W1[(8 * i + r) * 8 + 4]);
        W1reg[i][0] = a.x; W1reg[i][1] = a.y; W1reg[i][2] = a.z; W1reg[i][3] = a.w;
        W1reg[i][4] = b.x; W1reg[i][5] = b.y; W1reg[i][6] = b.z; W1reg[i][7] = b.w;
    }
    float W2col[8];
    #pragma unroll
    for (int i = 0; i < 8; ++i) W2col[i] = W2[i * 8 + r];
    float b1reg[8];
    #pragma unroll
    for (int j = 0; j < 8; ++j) b1reg[j] = b1[j];
    const float b2r = b2[r];

    const int node = (blockIdx.x * 4 + wave) * 8 + o;
    if (node >= N_NODES) return;  // whole octet exits together; shuffles stay octet-local

    const int beg = off[node];
    const int end = off[node + 1];

    float xqr[8];
    #pragma unroll
    for (int i = 0; i < 8; ++i) xqr[i] = xq[node * 64 + 8 * i + r];

    float acc[8];
    #pragma unroll
    for (int i = 0; i < 8; ++i) acc[i] = 0.f;

    for (int j = beg; j < end; ++j) {
        const float2 ep = epack[j];
        const float p   = ep.x;
        const int   dst = __float_as_int(ep.y);

        // ---- h1 partials: relu(xk - xq + p) @ W1 ----
        float part[8];
        #pragma unroll
        for (int jj = 0; jj < 8; ++jj) part[jj] = 0.f;
        #pragma unroll
        for (int i = 0; i < 8; ++i) {
            const float a  = xk[dst * 64 + 8 * i + r] - xqr[i] + p;
            const float ar = fmaxf(a, 0.f);
            #pragma unroll
            for (int jj = 0; jj < 8; ++jj)
                part[jj] = fmaf(ar, W1reg[i][jj], part[jj]);
        }
        #pragma unroll
        for (int jj = 0; jj < 8; ++jj) {
            part[jj] += __shfl_xor(part[jj], 1);
            part[jj] += __shfl_xor(part[jj], 2);
            part[jj] += __shfl_xor(part[jj], 4);
        }

        // ---- h2[r] = b2[r] + relu(h1) . W2[:, r] ----
        float h2 = b2r;
        #pragma unroll
        for (int jj = 0; jj < 8; ++jj) {
            const float h1 = fmaxf(part[jj] + b1reg[jj], 0.f);
            h2 = fmaf(h1, W2col[jj], h2);
        }

        // ---- softmax over the octet ----
        float mx = h2;
        mx = fmaxf(mx, __shfl_xor(mx, 1));
        mx = fmaxf(mx, __shfl_xor(mx, 2));
        mx = fmaxf(mx, __shfl_xor(mx, 4));
        const float ex = __expf(h2 - mx);
        float s = ex;
        s += __shfl_xor(s, 1);
        s += __shfl_xor(s, 2);
        s += __shfl_xor(s, 4);
        const float sel = ex / s;

        // ---- accumulate msg = (xv + p) * sel ----
        #pragma unroll
        for (int i = 0; i < 8; ++i)
            acc[i] = fmaf(xv[dst * 64 + 8 * i + r] + p, sel, acc[i]);
    }

    #pragma unroll
    for (int i = 0; i < 8; ++i)
        out[node * 64 + 8 * i + r] = acc[i];
}

extern "C" void kernel_launch(void* const* d_in, const int* in_sizes, int n_in,
                              void* d_out, int out_size, void* d_ws, size_t ws_size,
                              hipStream_t stream) {
    const float* q     = (const float*)d_in[0];
    const float* k     = (const float*)d_in[1];
    const float* v     = (const float*)d_in[2];
    const float* edges = (const float*)d_in[3];
    const int*   eidx  = (const int*)d_in[4];
    const float* Wq    = (const float*)d_in[5];
    const float* bq    = (const float*)d_in[6];
    const float* Wk    = (const float*)d_in[7];
    const float* bk    = (const float*)d_in[8];
    const float* Wv    = (const float*)d_in[9];
    const float* bv    = (const float*)d_in[10];
    const float* Wp    = (const float*)d_in[11];
    const float* bp    = (const float*)d_in[12];
    const float* W1    = (const float*)d_in[13];
    const float* b1    = (const float*)d_in[14];
    const float* W2    = (const float*)d_in[15];
    const float* b2    = (const float*)d_in[16];
    float* out = (float*)d_out;

    // workspace layout
    char* ws = (char*)d_ws;
    float* xq = (float*)ws;                          ws += (size_t)N_NODES * 64 * sizeof(float);
    float* xk = (float*)ws;                          ws += (size_t)N_NODES * 64 * sizeof(float);
    float* xv = (float*)ws;                          ws += (size_t)N_NODES * 64 * sizeof(float);
    int* cnt  = (int*)ws;                            ws += (size_t)(N_NODES + 64) * sizeof(int);
    int* off  = (int*)ws;                            ws += (size_t)(N_NODES + 64) * sizeof(int);
    float2* epack = (float2*)ws;                     ws += (size_t)E_EDGES * sizeof(float2);

    hipMemsetAsync(cnt, 0, (size_t)N_NODES * sizeof(int), stream);

    proj_kernel<<<dim3((N_NODES + 63) / 64), dim3(256), 0, stream>>>(
        q, k, v, Wq, bq, Wk, bk, Wv, bv, xq, xk, xv);

    hist_kernel<<<dim3(E_EDGES / 256), dim3(256), 0, stream>>>(eidx, cnt);

    scan_kernel<<<dim3(1), dim3(1024), 0, stream>>>(cnt, off);

    scatter_kernel<<<dim3(E_EDGES / 256), dim3(256), 0, stream>>>(
        eidx, edges, Wp, bp, cnt, epack);

    node_kernel<<<dim3((N_NODES + 31) / 32), dim3(256), 0, stream>>>(
        off, epack, W1, b1, W2, b2, xq, xk, xv, out);
}

// Round 3
// 216.693 us; speedup vs baseline: 1.8182x; 1.5334x over previous
//
#include <hip/hip_runtime.h>

#define N_NODES 50000
#define E_EDGES 800000
#define SCAN_TILE 1024
#define SCAN_NBLK ((N_NODES + SCAN_TILE - 1) / SCAN_TILE)   // 49

// ---------------------------------------------------------------------------
// Projection kernel: xq = q@Wq+bq, xk = k@Wk+bk, xv = v@Wv+bv  (N x 64 each)
// ---------------------------------------------------------------------------
__global__ __launch_bounds__(256) void proj_kernel(
    const float* __restrict__ qin, const float* __restrict__ kin, const float* __restrict__ vin,
    const float* __restrict__ Wq, const float* __restrict__ bq,
    const float* __restrict__ Wk, const float* __restrict__ bk,
    const float* __restrict__ Wv, const float* __restrict__ bv,
    float* __restrict__ xq, float* __restrict__ xk, float* __restrict__ xv)
{
    __shared__ float Ws[3 * 4096];
    const int tid = threadIdx.x;
    #pragma unroll
    for (int it = 0; it < 16; ++it) {
        const int idx = it * 256 + tid;
        Ws[idx]        = Wq[idx];
        Ws[4096 + idx] = Wk[idx];
        Ws[8192 + idx] = Wv[idx];
    }
    __syncthreads();

    const int cg = tid & 15;   // column group (4 cols)
    const int rg = tid >> 4;   // row group (4 rows)
    const int c0 = cg * 4;
    const int base = blockIdx.x * 64 + rg * 4;

    const float* ins[3]  = {qin, kin, vin};
    const float* bs[3]   = {bq, bk, bv};
    float*       outs[3] = {xq, xk, xv};

    int rowi[4];
    #pragma unroll
    for (int rr = 0; rr < 4; ++rr)
        rowi[rr] = (base + rr < N_NODES) ? (base + rr) : (N_NODES - 1);

    #pragma unroll
    for (int m = 0; m < 3; ++m) {
        const float* in = ins[m];
        const float* Wm = &Ws[m * 4096];
        float4 acc[4];
        const float4 b4 = *reinterpret_cast<const float4*>(&bs[m][c0]);
        #pragma unroll
        for (int rr = 0; rr < 4; ++rr) acc[rr] = b4;

        for (int kk = 0; kk < 64; kk += 4) {
            float4 rv[4];
            #pragma unroll
            for (int rr = 0; rr < 4; ++rr)
                rv[rr] = *reinterpret_cast<const float4*>(&in[rowi[rr] * 64 + kk]);
            #pragma unroll
            for (int dk = 0; dk < 4; ++dk) {
                const float4 w4 = *reinterpret_cast<const float4*>(&Wm[(kk + dk) * 64 + c0]);
                #pragma unroll
                for (int rr = 0; rr < 4; ++rr) {
                    const float xs = reinterpret_cast<const float*>(&rv[rr])[dk];
                    acc[rr].x = fmaf(xs, w4.x, acc[rr].x);
                    acc[rr].y = fmaf(xs, w4.y, acc[rr].y);
                    acc[rr].z = fmaf(xs, w4.z, acc[rr].z);
                    acc[rr].w = fmaf(xs, w4.w, acc[rr].w);
                }
            }
        }
        #pragma unroll
        for (int rr = 0; rr < 4; ++rr) {
            if (base + rr < N_NODES)
                *reinterpret_cast<float4*>(&outs[m][(base + rr) * 64 + c0]) = acc[rr];
        }
    }
}

// ---------------------------------------------------------------------------
// CSR build step 1: per-src degree histogram
// ---------------------------------------------------------------------------
__global__ __launch_bounds__(256) void hist_kernel(
    const int* __restrict__ eidx, int* __restrict__ cnt)
{
    const int e = blockIdx.x * 256 + threadIdx.x;
    atomicAdd(&cnt[eidx[2 * e]], 1);
}

// ---------------------------------------------------------------------------
// Hierarchical scan, step A: per-1024-element block sums (49 blocks).
// ---------------------------------------------------------------------------
__global__ __launch_bounds__(256) void scan_sums(
    const int* __restrict__ cnt, int* __restrict__ bsum)
{
    const int tid  = threadIdx.x;
    const int base = blockIdx.x * SCAN_TILE + tid * 4;
    int s = 0;
    if (base + 3 < N_NODES) {
        const int4 t = *reinterpret_cast<const int4*>(&cnt[base]);
        s = t.x + t.y + t.z + t.w;
    } else {
        #pragma unroll
        for (int i = 0; i < 4; ++i)
            if (base + i < N_NODES) s += cnt[base + i];
    }
    // wave reduce
    #pragma unroll
    for (int d = 1; d < 64; d <<= 1) s += __shfl_xor(s, d);
    __shared__ int ws[4];
    if ((tid & 63) == 0) ws[tid >> 6] = s;
    __syncthreads();
    if (tid == 0) bsum[blockIdx.x] = ws[0] + ws[1] + ws[2] + ws[3];
}

// ---------------------------------------------------------------------------
// Hierarchical scan, step B: exclusive scan of the 49 block sums (one wave).
// ---------------------------------------------------------------------------
__global__ __launch_bounds__(64) void scan_bsum(int* __restrict__ bsum)
{
    const int lane = threadIdx.x;
    const int v = (lane < SCAN_NBLK) ? bsum[lane] : 0;
    int incl = v;
    #pragma unroll
    for (int d = 1; d < 64; d <<= 1) {
        const int t = __shfl_up(incl, d);
        if (lane >= d) incl += t;
    }
    if (lane < SCAN_NBLK) bsum[lane] = incl - v;   // exclusive prefix
}

// ---------------------------------------------------------------------------
// Hierarchical scan, step C: local exclusive scan + block offset.
// Writes off[] and re-purposes cnt[] (in-place) as the scatter cursor.
// ---------------------------------------------------------------------------
__global__ __launch_bounds__(256) void scan_final(
    int* __restrict__ cnt, const int* __restrict__ bsum, int* __restrict__ off)
{
    const int tid  = threadIdx.x;
    const int base = blockIdx.x * SCAN_TILE + tid * 4;

    int v0 = 0, v1 = 0, v2 = 0, v3 = 0;
    if (base + 3 < N_NODES) {
        const int4 t = *reinterpret_cast<const int4*>(&cnt[base]);
        v0 = t.x; v1 = t.y; v2 = t.z; v3 = t.w;
    } else {
        if (base + 0 < N_NODES) v0 = cnt[base + 0];
        if (base + 1 < N_NODES) v1 = cnt[base + 1];
        if (base + 2 < N_NODES) v2 = cnt[base + 2];
        if (base + 3 < N_NODES) v3 = cnt[base + 3];
    }
    const int s = v0 + v1 + v2 + v3;

    // wave-inclusive scan of per-thread sums
    int incl = s;
    #pragma unroll
    for (int d = 1; d < 64; d <<= 1) {
        const int t = __shfl_up(incl, d);
        if ((tid & 63) >= d) incl += t;
    }
    __shared__ int wsum[4];
    const int wave = tid >> 6;
    if ((tid & 63) == 63) wsum[wave] = incl;
    __syncthreads();
    int woff = 0;
    #pragma unroll
    for (int w = 0; w < 3; ++w)
        if (w < wave) woff += wsum[w];

    int run = bsum[blockIdx.x] + woff + (incl - s);   // exclusive prefix
    if (base + 0 < N_NODES) { off[base + 0] = run; cnt[base + 0] = run; run += v0; }
    if (base + 1 < N_NODES) { off[base + 1] = run; cnt[base + 1] = run; run += v1; }
    if (base + 2 < N_NODES) { off[base + 2] = run; cnt[base + 2] = run; run += v2; }
    if (base + 3 < N_NODES) { off[base + 3] = run; cnt[base + 3] = run; run += v3; }

    if (blockIdx.x == 0 && tid == 0) off[N_NODES] = E_EDGES;
}

// ---------------------------------------------------------------------------
// CSR build step 3 (+ p_r precompute): scatter {p_r, dst} to CSR slot.
// ---------------------------------------------------------------------------
__global__ __launch_bounds__(256) void scatter_kernel(
    const int* __restrict__ eidx, const float* __restrict__ edges,
    const float* __restrict__ Wp, const float* __restrict__ bp,
    int* __restrict__ cursor, float2* __restrict__ epack)
{
    const int e = blockIdx.x * 256 + threadIdx.x;
    const int src = eidx[2 * e];
    const int dst = eidx[2 * e + 1];

    float pr = bp[0];
    #pragma unroll
    for (int q4 = 0; q4 < 4; ++q4) {
        const float4 ev = *reinterpret_cast<const float4*>(&edges[e * 16 + q4 * 4]);
        const float4 wv = *reinterpret_cast<const float4*>(&Wp[q4 * 4]);
        pr = fmaf(ev.x, wv.x, pr);
        pr = fmaf(ev.y, wv.y, pr);
        pr = fmaf(ev.z, wv.z, pr);
        pr = fmaf(ev.w, wv.w, pr);
    }

    const int pos = atomicAdd(&cursor[src], 1);
    epack[pos] = make_float2(pr, __int_as_float(dst));
}

// ---------------------------------------------------------------------------
// Node kernel: one octet (8 lanes) per aggregation node. Lane r owns channels
// c = 8*i + r. Accumulates the 64-ch message in registers, writes out once.
// ---------------------------------------------------------------------------
__global__ __launch_bounds__(256) void node_kernel(
    const int* __restrict__ off, const float2* __restrict__ epack,
    const float* __restrict__ W1, const float* __restrict__ b1,
    const float* __restrict__ W2, const float* __restrict__ b2,
    const float* __restrict__ xq, const float* __restrict__ xk, const float* __restrict__ xv,
    float* __restrict__ out)
{
    const int tid  = threadIdx.x;
    const int lane = tid & 63;
    const int o    = lane >> 3;   // octet within wave
    const int r    = lane & 7;    // lane within octet
    const int wave = tid >> 6;

    // ---- preload weights into registers ----
    float W1reg[8][8];   // rows c = 8*i + r, all 8 output cols
    #pragma unroll
    for (int i = 0; i < 8; ++i) {
        const float4 a = *reinterpret_cast<const float4*>(&W1[(8 * i + r) * 8]);
        const float4 b = *reinterpret_cast<const float4*>(&W1[(8 * i + r) * 8 + 4]);
        W1reg[i][0] = a.x; W1reg[i][1] = a.y; W1reg[i][2] = a.z; W1reg[i][3] = a.w;
        W1reg[i][4] = b.x; W1reg[i][5] = b.y; W1reg[i][6] = b.z; W1reg[i][7] = b.w;
    }
    float W2col[8];
    #pragma unroll
    for (int i = 0; i < 8; ++i) W2col[i] = W2[i * 8 + r];
    float b1reg[8];
    #pragma unroll
    for (int j = 0; j < 8; ++j) b1reg[j] = b1[j];
    const float b2r = b2[r];

    const int node = (blockIdx.x * 4 + wave) * 8 + o;
    if (node >= N_NODES) return;  // whole octet exits together

    const int beg = off[node];
    const int end = off[node + 1];

    float xqr[8];
    #pragma unroll
    for (int i = 0; i < 8; ++i) xqr[i] = xq[node * 64 + 8 * i + r];

    float acc[8];
    #pragma unroll
    for (int i = 0; i < 8; ++i) acc[i] = 0.f;

    for (int j = beg; j < end; ++j) {
        const float2 ep = epack[j];
        const float p   = ep.x;
        const int   dst = __float_as_int(ep.y);

        // ---- h1 partials: relu(xk - xq + p) @ W1 ----
        float part[8];
        #pragma unroll
        for (int jj = 0; jj < 8; ++jj) part[jj] = 0.f;
        #pragma unroll
        for (int i = 0; i < 8; ++i) {
            const float a  = xk[dst * 64 + 8 * i + r] - xqr[i] + p;
            const float ar = fmaxf(a, 0.f);
            #pragma unroll
            for (int jj = 0; jj < 8; ++jj)
                part[jj] = fmaf(ar, W1reg[i][jj], part[jj]);
        }
        #pragma unroll
        for (int jj = 0; jj < 8; ++jj) {
            part[jj] += __shfl_xor(part[jj], 1);
            part[jj] += __shfl_xor(part[jj], 2);
            part[jj] += __shfl_xor(part[jj], 4);
        }

        // ---- h2[r] = b2[r] + relu(h1) . W2[:, r] ----
        float h2 = b2r;
        #pragma unroll
        for (int jj = 0; jj < 8; ++jj) {
            const float h1 = fmaxf(part[jj] + b1reg[jj], 0.f);
            h2 = fmaf(h1, W2col[jj], h2);
        }

        // ---- softmax over the octet ----
        float mx = h2;
        mx = fmaxf(mx, __shfl_xor(mx, 1));
        mx = fmaxf(mx, __shfl_xor(mx, 2));
        mx = fmaxf(mx, __shfl_xor(mx, 4));
        const float ex = __expf(h2 - mx);
        float s = ex;
        s += __shfl_xor(s, 1);
        s += __shfl_xor(s, 2);
        s += __shfl_xor(s, 4);
        const float sel = ex / s;

        // ---- accumulate msg = (xv + p) * sel ----
        #pragma unroll
        for (int i = 0; i < 8; ++i)
            acc[i] = fmaf(xv[dst * 64 + 8 * i + r] + p, sel, acc[i]);
    }

    #pragma unroll
    for (int i = 0; i < 8; ++i)
        out[node * 64 + 8 * i + r] = acc[i];
}

extern "C" void kernel_launch(void* const* d_in, const int* in_sizes, int n_in,
                              void* d_out, int out_size, void* d_ws, size_t ws_size,
                              hipStream_t stream) {
    const float* q     = (const float*)d_in[0];
    const float* k     = (const float*)d_in[1];
    const float* v     = (const float*)d_in[2];
    const float* edges = (const float*)d_in[3];
    const int*   eidx  = (const int*)d_in[4];
    const float* Wq    = (const float*)d_in[5];
    const float* bq    = (const float*)d_in[6];
    const float* Wk    = (const float*)d_in[7];
    const float* bk    = (const float*)d_in[8];
    const float* Wv    = (const float*)d_in[9];
    const float* bv    = (const float*)d_in[10];
    const float* Wp    = (const float*)d_in[11];
    const float* bp    = (const float*)d_in[12];
    const float* W1    = (const float*)d_in[13];
    const float* b1    = (const float*)d_in[14];
    const float* W2    = (const float*)d_in[15];
    const float* b2    = (const float*)d_in[16];
    float* out = (float*)d_out;

    // workspace layout
    char* ws = (char*)d_ws;
    float* xq = (float*)ws;                          ws += (size_t)N_NODES * 64 * sizeof(float);
    float* xk = (float*)ws;                          ws += (size_t)N_NODES * 64 * sizeof(float);
    float* xv = (float*)ws;                          ws += (size_t)N_NODES * 64 * sizeof(float);
    int* cnt  = (int*)ws;                            ws += (size_t)(N_NODES + 64) * sizeof(int);
    int* off  = (int*)ws;                            ws += (size_t)(N_NODES + 64) * sizeof(int);
    int* bsum = (int*)ws;                            ws += (size_t)64 * sizeof(int);
    float2* epack = (float2*)ws;                     ws += (size_t)E_EDGES * sizeof(float2);

    hipMemsetAsync(cnt, 0, (size_t)N_NODES * sizeof(int), stream);

    proj_kernel<<<dim3((N_NODES + 63) / 64), dim3(256), 0, stream>>>(
        q, k, v, Wq, bq, Wk, bk, Wv, bv, xq, xk, xv);

    hist_kernel<<<dim3(E_EDGES / 256), dim3(256), 0, stream>>>(eidx, cnt);

    scan_sums<<<dim3(SCAN_NBLK), dim3(256), 0, stream>>>(cnt, bsum);
    scan_bsum<<<dim3(1), dim3(64), 0, stream>>>(bsum);
    scan_final<<<dim3(SCAN_NBLK), dim3(256), 0, stream>>>(cnt, bsum, off);

    scatter_kernel<<<dim3(E_EDGES / 256), dim3(256), 0, stream>>>(
        eidx, edges, Wp, bp, cnt, epack);

    node_kernel<<<dim3((N_NODES + 31) / 32), dim3(256), 0, stream>>>(
        off, epack, W1, b1, W2, b2, xq, xk, xv, out);
}